// Round 5
// baseline (29460.083 us; speedup 1.0000x reference)
//
#include <hip/hip_runtime.h>
#include <math.h>

#define TT 512
#define BB 64
#define II 512
#define HH 1024
#define OO 512
#define KK 1536   // I + H

#define GRID 256
#define NTHR 512

__device__ __forceinline__ float sigmoidf_(float v) {
    return 1.0f / (1.0f + __expf(-v));
}

// ---- write-through (LLC) store for mutable shared state ----
__device__ __forceinline__ void st_sys(float* p, float v) {
    asm volatile("global_store_dword %0, %1, off sc0 sc1"
                 :: "v"(p), "v"(v) : "memory");
}

#define DOT4(accv, av, wv) do { \
    (accv) = fmaf((av).x, (wv).x, (accv)); \
    (accv) = fmaf((av).y, (wv).y, (accv)); \
    (accv) = fmaf((av).z, (wv).z, (accv)); \
    (accv) = fmaf((av).w, (wv).w, (accv)); } while (0)

// Hierarchical grid barrier: 8 group counters (32 blocks each, 128B apart)
// + 1 root. Release: drain write-through stores. Acquire: L1+L2 invalidate
// so plain cached loads see fresh LLC data. Root grows by 8 per barrier.
__device__ __forceinline__ void gbar(unsigned* cb, unsigned target8, int tid, int grp)
{
    asm volatile("s_waitcnt vmcnt(0)" ::: "memory");
    __syncthreads();
    if (tid == 0) {
        unsigned old = __hip_atomic_fetch_add(&cb[grp * 32], 1u,
                           __ATOMIC_RELAXED, __HIP_MEMORY_SCOPE_AGENT);
        if ((old & 31u) == 31u)
            __hip_atomic_fetch_add(&cb[256], 1u,
                __ATOMIC_RELAXED, __HIP_MEMORY_SCOPE_AGENT);
        while (__hip_atomic_load(&cb[256], __ATOMIC_RELAXED,
                   __HIP_MEMORY_SCOPE_AGENT) < target8)
            __builtin_amdgcn_s_sleep(1);
    }
    __syncthreads();
    __builtin_amdgcn_fence(__ATOMIC_ACQUIRE, "agent");   // buffer_inv: L1+L2
}

__global__ void zero_ctr(unsigned* c) {
    for (int i = 0; i < 8; ++i) c[i * 32] = 0u;
    c[256] = 0u;
}

// ---- reduce-scatter shuffles: lane ko ends with the total for cell c=ko ----
// 31 shfl instead of 160 (rs32); all indices compile-time (no scratch).
__device__ __forceinline__ float rs32(float (&v)[32], int ko)
{
    const bool h16 = (ko & 16) != 0;
    float a[16];
    #pragma unroll
    for (int k = 0; k < 16; ++k) {
        float send = h16 ? v[k] : v[k + 16];
        float keep = h16 ? v[k + 16] : v[k];
        a[k] = keep + __shfl_xor(send, 16);
    }
    const bool h8 = (ko & 8) != 0;
    float b[8];
    #pragma unroll
    for (int k = 0; k < 8; ++k) {
        float send = h8 ? a[k] : a[k + 8];
        float keep = h8 ? a[k + 8] : a[k];
        b[k] = keep + __shfl_xor(send, 8);
    }
    const bool h4 = (ko & 4) != 0;
    float c[4];
    #pragma unroll
    for (int k = 0; k < 4; ++k) {
        float send = h4 ? b[k] : b[k + 4];
        float keep = h4 ? b[k + 4] : b[k];
        c[k] = keep + __shfl_xor(send, 4);
    }
    const bool h2 = (ko & 2) != 0;
    float d[2];
    #pragma unroll
    for (int k = 0; k < 2; ++k) {
        float send = h2 ? c[k] : c[k + 2];
        float keep = h2 ? c[k + 2] : c[k];
        d[k] = keep + __shfl_xor(send, 2);
    }
    const bool h1 = (ko & 1) != 0;
    float send = h1 ? d[0] : d[1];
    float keep = h1 ? d[1] : d[0];
    return keep + __shfl_xor(send, 1);
}

// 16 cells; result valid on lanes ko<16.
__device__ __forceinline__ float rs16(float (&v)[16], int ko)
{
    float a[16];
    #pragma unroll
    for (int k = 0; k < 16; ++k) a[k] = v[k] + __shfl_xor(v[k], 16);
    const bool h8 = (ko & 8) != 0;
    float b[8];
    #pragma unroll
    for (int k = 0; k < 8; ++k) {
        float send = h8 ? a[k] : a[k + 8];
        float keep = h8 ? a[k + 8] : a[k];
        b[k] = keep + __shfl_xor(send, 8);
    }
    const bool h4 = (ko & 4) != 0;
    float c[4];
    #pragma unroll
    for (int k = 0; k < 4; ++k) {
        float send = h4 ? b[k] : b[k + 4];
        float keep = h4 ? b[k + 4] : b[k];
        c[k] = keep + __shfl_xor(send, 4);
    }
    const bool h2 = (ko & 2) != 0;
    float d[2];
    #pragma unroll
    for (int k = 0; k < 2; ++k) {
        float send = h2 ? c[k] : c[k + 2];
        float keep = h2 ? c[k + 2] : c[k];
        d[k] = keep + __shfl_xor(send, 2);
    }
    const bool h1 = (ko & 1) != 0;
    float send = h1 ? d[0] : d[1];
    float keep = h1 ? d[1] : d[0];
    return keep + __shfl_xor(send, 1);
}

// 8 cells; result valid on lanes ko<8.
__device__ __forceinline__ float rs8(float (&v)[8], int ko)
{
    float a[8];
    #pragma unroll
    for (int k = 0; k < 8; ++k) {
        float t = v[k] + __shfl_xor(v[k], 16);
        a[k] = t + __shfl_xor(t, 8);
    }
    const bool h4 = (ko & 4) != 0;
    float c[4];
    #pragma unroll
    for (int k = 0; k < 4; ++k) {
        float send = h4 ? a[k] : a[k + 4];
        float keep = h4 ? a[k + 4] : a[k];
        c[k] = keep + __shfl_xor(send, 4);
    }
    const bool h2 = (ko & 2) != 0;
    float d[2];
    #pragma unroll
    for (int k = 0; k < 2; ++k) {
        float send = h2 ? c[k] : c[k + 2];
        float keep = h2 ? c[k + 2] : c[k];
        d[k] = keep + __shfl_xor(send, 2);
    }
    const bool h1 = (ko & 1) != 0;
    float send = h1 ? d[0] : d[1];
    float keep = h1 ? d[1] : d[0];
    return keep + __shfl_xor(send, 1);
}

// Persistent kernel, 256 blocks x 512 threads, 1 block/CU.
// R4 register-tiled split-K, plus: (1) reduce-scatter shuffle reductions,
// (2) out-GEMM fused into phase A's h-streaming loop (h read once),
// (3) x float4s carried in registers from phase A to phase B,
// (4) h-old cell prefetched during A (only zb read post-barrier).
__global__ __launch_bounds__(NTHR, 2) void gru_fused(
    const float* __restrict__ x,
    const float* __restrict__ Wz, const float* __restrict__ bz,
    const float* __restrict__ Wr, const float* __restrict__ br,
    const float* __restrict__ Wh, const float* __restrict__ bh,
    const float* __restrict__ Wo, const float* __restrict__ bo,
    float* __restrict__ out, float* __restrict__ ws)
{
    __shared__ float wgA[8 * KK];    // 48 KB : gate (z or r), 8 cols
    __shared__ float whB[4 * KK];    // 24 KB : candidate, 4 cols
    __shared__ float woO[2 * HH];    //  8 KB : out, 2 cols

    float* h  = ws;                  // [64][1024]
    float* hr = ws + 1 * 65536;      // h * r
    float* zb = ws + 2 * 65536;      // sigmoid(z)
    unsigned* cb = (unsigned*)(ws + 3 * 65536);   // barrier counters

    const int bid = blockIdx.x;
    const int tid = threadIdx.x;
    const int grp = bid >> 5;

    const bool is_r = (bid & 128) != 0;
    const float* Wg = is_r ? Wr : Wz;
    const int j0  = (bid & 127) * 8;
    const int j0h = bid * 4;
    const int j0o = bid * 2;

    // ---- stage weight slices to LDS, [j][k] flat (once) ----
    for (int i = tid; i < KK * 8; i += NTHR)
        wgA[(i & 7) * KK + (i >> 3)] = Wg[(size_t)(i >> 3) * HH + j0 + (i & 7)];
    for (int i = tid; i < KK * 4; i += NTHR)
        whB[(i & 3) * KK + (i >> 2)] = Wh[(size_t)(i >> 2) * HH + j0h + (i & 3)];
    for (int i = tid; i < HH * 2; i += NTHR)
        woO[(i & 1) * HH + (i >> 1)] = Wo[(size_t)(i >> 1) * OO + j0o + (i & 1)];

    // ---- init h = 0 (ws is poisoned) ----
    {
        int g = bid * NTHR + tid;
        if (g < BB * HH) st_sys(&h[g], 0.0f);
    }

    // ---- per-thread fixed mappings ----
    const int ko = tid & 31;          // k-slice
    const int bg = tid >> 5;          // batch group (4 batches)
    const int b0 = bg * 4;

    const int bA = b0 + (ko >> 3), jA = j0 + (ko & 7);      // A cell (all lanes)
    const float biasA = is_r ? br[jA] : bz[jA];

    const int bB = b0 + (ko >> 2), jB = j0h + (ko & 3);     // B cell (ko<16)
    const float biasB = bh[jB];

    const int bO = b0 + (ko >> 1), jO = j0o + (ko & 1);     // O cell (ko<8)
    const float biasO = bo[jO];

    const float4* wg4 = (const float4*)wgA;
    const float4* wh4 = (const float4*)whB;
    const float4* wo4 = (const float4*)woO;

    unsigned tgt = 8;
    gbar(cb, tgt, tid, grp);

    for (int t = 0; t < TT; ++t) {
        const float* xt = x + (size_t)t * BB * II;

        const float4* xp0 = (const float4*)(xt + (size_t)(b0 + 0) * II);
        const float4* xp1 = (const float4*)(xt + (size_t)(b0 + 1) * II);
        const float4* xp2 = (const float4*)(xt + (size_t)(b0 + 2) * II);
        const float4* xp3 = (const float4*)(xt + (size_t)(b0 + 3) * II);
        const float4* hp0 = (const float4*)(h + (size_t)(b0 + 0) * HH);
        const float4* hp1 = (const float4*)(h + (size_t)(b0 + 1) * HH);
        const float4* hp2 = (const float4*)(h + (size_t)(b0 + 2) * HH);
        const float4* hp3 = (const float4*)(h + (size_t)(b0 + 3) * HH);

        float4 xr[4][4];   // x carry A->B (u<4)

        // ===== Phase A : gate (8 cols) + out[t-1] (2 cols) fused =====
        const size_t iA = (size_t)bA * HH + jA;
        const size_t iB = (size_t)bB * HH + jB;
        {
            float hpre = 0.f;
            if (is_r) hpre = h[iA];              // for hr product
            float hpre2 = 0.f;
            if (ko < 16) hpre2 = h[iB];          // carried to phase B

            float accA[32], accO[8];
            #pragma unroll
            for (int c = 0; c < 32; ++c) accA[c] = 0.f;
            #pragma unroll
            for (int c = 0; c < 8; ++c) accO[c] = 0.f;

            #pragma unroll
            for (int u = 0; u < 12; ++u) {
                const int kq = ko + 32 * u;
                float4 av0, av1, av2, av3;
                if (u < 4) {
                    av0 = xp0[kq]; av1 = xp1[kq];
                    av2 = xp2[kq]; av3 = xp3[kq];
                    xr[u][0] = av0; xr[u][1] = av1;
                    xr[u][2] = av2; xr[u][3] = av3;
                } else {
                    av0 = hp0[kq - 128]; av1 = hp1[kq - 128];
                    av2 = hp2[kq - 128]; av3 = hp3[kq - 128];
                }
                #pragma unroll
                for (int jj = 0; jj < 8; ++jj) {
                    float4 wv = wg4[jj * 384 + kq];
                    DOT4(accA[0 * 8 + jj], av0, wv);
                    DOT4(accA[1 * 8 + jj], av1, wv);
                    DOT4(accA[2 * 8 + jj], av2, wv);
                    DOT4(accA[3 * 8 + jj], av3, wv);
                }
                if (u >= 4) {                    // fused out-GEMM (h only)
                    float4 w0 = wo4[kq - 128];
                    float4 w1 = wo4[256 + (kq - 128)];
                    DOT4(accO[0], av0, w0); DOT4(accO[1], av0, w1);
                    DOT4(accO[2], av1, w0); DOT4(accO[3], av1, w1);
                    DOT4(accO[4], av2, w0); DOT4(accO[5], av2, w1);
                    DOT4(accO[6], av3, w0); DOT4(accO[7], av3, w1);
                }
            }

            float cellA = rs32(accA, ko);
            float val = sigmoidf_(biasA + cellA);
            if (is_r) st_sys(&hr[iA], hpre * val);
            else      st_sys(&zb[iA], val);

            float cellO = rs8(accO, ko);
            if (ko < 8 && t > 0)
                out[(size_t)(t - 1) * BB * OO + (size_t)bO * OO + jO]
                    = biasO + cellO;

            tgt += 8; gbar(cb, tgt, tid, grp);

            // ===== Phase B : candidate + h update =====
            float zpre = 0.f;
            if (ko < 16) zpre = zb[iB];          // written in A by z-blocks

            const float4* rp0 = (const float4*)(hr + (size_t)(b0 + 0) * HH);
            const float4* rp1 = (const float4*)(hr + (size_t)(b0 + 1) * HH);
            const float4* rp2 = (const float4*)(hr + (size_t)(b0 + 2) * HH);
            const float4* rp3 = (const float4*)(hr + (size_t)(b0 + 3) * HH);

            float accB[16];
            #pragma unroll
            for (int c = 0; c < 16; ++c) accB[c] = 0.f;

            #pragma unroll
            for (int u = 0; u < 12; ++u) {
                const int kq = ko + 32 * u;
                float4 av0, av1, av2, av3;
                if (u < 4) {                     // x from registers
                    av0 = xr[u][0]; av1 = xr[u][1];
                    av2 = xr[u][2]; av3 = xr[u][3];
                } else {
                    av0 = rp0[kq - 128]; av1 = rp1[kq - 128];
                    av2 = rp2[kq - 128]; av3 = rp3[kq - 128];
                }
                #pragma unroll
                for (int jj = 0; jj < 4; ++jj) {
                    float4 wv = wh4[jj * 384 + kq];
                    DOT4(accB[0 * 4 + jj], av0, wv);
                    DOT4(accB[1 * 4 + jj], av1, wv);
                    DOT4(accB[2 * 4 + jj], av2, wv);
                    DOT4(accB[3 * 4 + jj], av3, wv);
                }
            }

            float cellB = rs16(accB, ko);
            if (ko < 16) {
                float cv = sigmoidf_(biasB + cellB);
                st_sys(&h[iB], zpre * hpre2 + (1.0f - zpre) * cv);
            }
        }
        tgt += 8; gbar(cb, tgt, tid, grp);
    }

    // ---- tail: out[T-1] = h_{T-1} @ Wo ----
    {
        const float4* hp0 = (const float4*)(h + (size_t)(b0 + 0) * HH);
        const float4* hp1 = (const float4*)(h + (size_t)(b0 + 1) * HH);
        const float4* hp2 = (const float4*)(h + (size_t)(b0 + 2) * HH);
        const float4* hp3 = (const float4*)(h + (size_t)(b0 + 3) * HH);
        float accO[8];
        #pragma unroll
        for (int c = 0; c < 8; ++c) accO[c] = 0.f;
        #pragma unroll
        for (int u = 0; u < 8; ++u) {
            const int kq = ko + 32 * u;
            float4 av0 = hp0[kq], av1 = hp1[kq];
            float4 av2 = hp2[kq], av3 = hp3[kq];
            float4 w0 = wo4[kq];
            float4 w1 = wo4[256 + kq];
            DOT4(accO[0], av0, w0); DOT4(accO[1], av0, w1);
            DOT4(accO[2], av1, w0); DOT4(accO[3], av1, w1);
            DOT4(accO[4], av2, w0); DOT4(accO[5], av2, w1);
            DOT4(accO[6], av3, w0); DOT4(accO[7], av3, w1);
        }
        float cellO = rs8(accO, ko);
        if (ko < 8)
            out[(size_t)(TT - 1) * BB * OO + (size_t)bO * OO + jO]
                = biasO + cellO;
    }
}

extern "C" void kernel_launch(void* const* d_in, const int* in_sizes, int n_in,
                              void* d_out, int out_size, void* d_ws, size_t ws_size,
                              hipStream_t stream)
{
    (void)in_sizes; (void)n_in; (void)out_size; (void)ws_size;
    const float* x  = (const float*)d_in[0];
    const float* Wz = (const float*)d_in[1];
    const float* bz = (const float*)d_in[2];
    const float* Wr = (const float*)d_in[3];
    const float* br = (const float*)d_in[4];
    const float* Wh = (const float*)d_in[5];
    const float* bh = (const float*)d_in[6];
    const float* Wo = (const float*)d_in[7];
    const float* bo = (const float*)d_in[8];
    float* out = (float*)d_out;
    float* ws  = (float*)d_ws;   // 3*65536 floats state + barrier counters

    zero_ctr<<<1, 1, 0, stream>>>((unsigned*)(ws + 3 * 65536));

    void* args[] = { (void*)&x, (void*)&Wz, (void*)&bz, (void*)&Wr, (void*)&br,
                     (void*)&Wh, (void*)&bh, (void*)&Wo, (void*)&bo,
                     (void*)&out, (void*)&ws };
    hipLaunchCooperativeKernel(reinterpret_cast<void*>(gru_fused),
                               dim3(GRID), dim3(NTHR), args, 0, stream);
}